// Round 1
// baseline (1149.607 us; speedup 1.0000x reference)
//
#include <hip/hip_runtime.h>
#include <hip/hip_bf16.h>

#define NN 8192
#define HH 256
#define RR 3

#define BM 128
#define BK 64
#define SPLIT 4
#define KSLICE (NN / SPLIT)   // 2048

typedef __attribute__((ext_vector_type(8))) short     bf16x8;
typedef __attribute__((ext_vector_type(4))) float     f32x4;
typedef __attribute__((ext_vector_type(4))) unsigned short u16x4;
typedef __attribute__((ext_vector_type(8))) unsigned short u16x8;

__device__ __forceinline__ unsigned short f2bf(float f) {
    unsigned int u = __builtin_bit_cast(unsigned int, f);
    u += 0x7FFF + ((u >> 16) & 1);   // round-to-nearest-even
    return (unsigned short)(u >> 16);
}

// ---------------------------------------------------------------------------
// Kernel A: xw_t[r][c][k] = sum_h x[k][h] * W[r][h][c], stored bf16, K-major.
// Exact fp32 accumulate, one rounding at the end.
// Block: 256 threads (thread = output column c), tile = 16 k-rows.
// ---------------------------------------------------------------------------
__global__ __launch_bounds__(256) void xw_kernel(
    const float* __restrict__ x, const float* __restrict__ W,
    unsigned short* __restrict__ xwt)
{
    const int r  = blockIdx.y;
    const int k0 = blockIdx.x * 16;
    const int c  = threadIdx.x;

    __shared__ float xs[16][HH];   // 16 KB

    // stage x[k0..k0+16)[0..256) : 1024 float4s, 256 threads -> 4 each
    for (int idx = threadIdx.x; idx < 16 * (HH / 4); idx += 256) {
        const int i  = idx >> 6;         // / 64
        const int h4 = idx & 63;
        ((f32x4*)xs[i])[h4] = ((const f32x4*)(x + (size_t)(k0 + i) * HH))[h4];
    }
    __syncthreads();

    float acc[16];
#pragma unroll
    for (int i = 0; i < 16; ++i) acc[i] = 0.f;

    const float* Wr = W + (size_t)r * HH * HH;
    for (int h = 0; h < HH; h += 8) {
        // coalesced: 256 threads read 256 consecutive floats per j (L2-hot)
        float w0 = Wr[(h + 0) * HH + c];
        float w1 = Wr[(h + 1) * HH + c];
        float w2 = Wr[(h + 2) * HH + c];
        float w3 = Wr[(h + 3) * HH + c];
        float w4 = Wr[(h + 4) * HH + c];
        float w5 = Wr[(h + 5) * HH + c];
        float w6 = Wr[(h + 6) * HH + c];
        float w7 = Wr[(h + 7) * HH + c];
#pragma unroll
        for (int i = 0; i < 16; ++i) {
            const f32x4 a = *(const f32x4*)&xs[i][h];
            const f32x4 b = *(const f32x4*)&xs[i][h + 4];
            acc[i] += a.x * w0 + a.y * w1 + a.z * w2 + a.w * w3
                    + b.x * w4 + b.y * w5 + b.z * w6 + b.w * w7;
        }
    }

    // pack to bf16 and store 2x16B (K-major: xwt[(r*HH + c)*NN + k])
    u16x8 lo, hi;
#pragma unroll
    for (int i = 0; i < 8; ++i) { lo[i] = f2bf(acc[i]); hi[i] = f2bf(acc[i + 8]); }
    u16x8* dst = (u16x8*)(xwt + ((size_t)r * HH + c) * NN + k0);
    dst[0] = lo;
    dst[1] = hi;
}

// ---------------------------------------------------------------------------
// Kernel B: out[m0..m0+128)[0..256) += bf16(adjs[r][m][k]) * xw_t[r][c][k]
// MFMA 16x16x32 bf16, fp32 accum. Split-K (SPLIT slices per relation),
// fp32 atomicAdd epilogue. XOR-swizzled LDS tiles (both stored row x K,
// K contiguous, 128B rows; byte ^= (row&7)<<4).
// 512 threads = 8 waves (2M x 4N), wave tile 64x64.
// ---------------------------------------------------------------------------
__global__ __launch_bounds__(512) void rgcn_spmm(
    const float* __restrict__ adjs, const unsigned short* __restrict__ xwt,
    float* __restrict__ out)
{
    __shared__ unsigned short As[BM * BK];   // 16 KB
    __shared__ unsigned short Bs[HH * BK];   // 32 KB

    // XCD-grouped swizzle: 768 blocks = 8 XCDs x 96; blocks sharing a B-slice
    // land on the same XCD so the 1MB xw_t slice stays L2-resident.
    const int id  = blockIdx.x + gridDim.x * blockIdx.y;  // 0..767
    const int swz = (id & 7) * 96 + (id >> 3);            // bijective (768 = 8*96)
    const int bx  = swz & 63;
    const int by  = swz >> 6;

    const int m0    = bx * BM;
    const int r     = by / SPLIT;
    const int slice = by % SPLIT;
    const int k0    = slice * KSLICE;

    const float*          A = adjs + (size_t)r * NN * NN;
    const unsigned short* B = xwt  + (size_t)r * HH * NN;

    const int tid  = threadIdx.x;
    const int lane = tid & 63;
    const int wave = tid >> 6;
    const int wm   = wave >> 2;   // 0..1
    const int wn   = wave & 3;    // 0..3

    f32x4 acc[4][4];
#pragma unroll
    for (int m = 0; m < 4; ++m)
#pragma unroll
        for (int n = 0; n < 4; ++n) acc[m][n] = (f32x4){0.f, 0.f, 0.f, 0.f};

    for (int kk = 0; kk < KSLICE; kk += BK) {
        const int kbase = k0 + kk;

        // ---- stage A: 128 rows x 64 k, fp32 -> bf16, swizzled
        // thread: 4 passes x (float4 load + cvt + 8B LDS write)
#pragma unroll
        for (int p = 0; p < 4; ++p) {
            const int row = p * 32 + (tid >> 4);
            const int col = (tid & 15) << 2;
            const f32x4 v = *(const f32x4*)(A + (size_t)(m0 + row) * NN + kbase + col);
            u16x4 b4;
            b4.x = f2bf(v.x); b4.y = f2bf(v.y); b4.z = f2bf(v.z); b4.w = f2bf(v.w);
            const int byte = (col << 1) ^ ((row & 7) << 4);
            *(u16x4*)((char*)(As + row * BK) + byte) = b4;
        }
        // ---- stage B: 256 "rows" (=out cols) x 64 k bf16, swizzled
#pragma unroll
        for (int p = 0; p < 4; ++p) {
            const int crow  = p * 64 + (tid >> 3);
            const int chunk = tid & 7;
            const u16x8 v = *(const u16x8*)(B + (size_t)crow * NN + kbase + chunk * 8);
            const int byte = ((chunk << 4) ^ ((crow & 7) << 4));
            *(u16x8*)((char*)(Bs + crow * BK) + byte) = v;
        }
        __syncthreads();

        // ---- compute: 2 k-substeps x 4m x 4n MFMAs
#pragma unroll
        for (int ks = 0; ks < 2; ++ks) {
            bf16x8 af[4], bfr[4];
#pragma unroll
            for (int m = 0; m < 4; ++m) {
                const int row  = wm * 64 + m * 16 + (lane & 15);
                const int col  = ks * 32 + (lane >> 4) * 8;
                const int byte = (col << 1) ^ ((row & 7) << 4);
                af[m] = *(const bf16x8*)((const char*)(As + row * BK) + byte);
            }
#pragma unroll
            for (int n = 0; n < 4; ++n) {
                const int crow = wn * 64 + n * 16 + (lane & 15);
                const int col  = ks * 32 + (lane >> 4) * 8;
                const int byte = (col << 1) ^ ((crow & 7) << 4);
                bfr[n] = *(const bf16x8*)((const char*)(Bs + crow * BK) + byte);
            }
#pragma unroll
            for (int m = 0; m < 4; ++m)
#pragma unroll
                for (int n = 0; n < 4; ++n)
                    acc[m][n] = __builtin_amdgcn_mfma_f32_16x16x32_bf16(
                        af[m], bfr[n], acc[m][n], 0, 0, 0);
        }
        __syncthreads();
    }

    // ---- epilogue: fp32 atomic accumulate (12 partials per output elem)
    // C/D layout (m89-verified): col = lane&15, row = (lane>>4)*4 + j
#pragma unroll
    for (int m = 0; m < 4; ++m) {
#pragma unroll
        for (int n = 0; n < 4; ++n) {
            const int colb = wn * 64 + n * 16 + (lane & 15);
            const int rowb = m0 + wm * 64 + m * 16 + (lane >> 4) * 4;
#pragma unroll
            for (int j = 0; j < 4; ++j)
                atomicAdd(out + (size_t)(rowb + j) * HH + colb, acc[m][n][j]);
        }
    }
}

extern "C" void kernel_launch(void* const* d_in, const int* in_sizes, int n_in,
                              void* d_out, int out_size, void* d_ws, size_t ws_size,
                              hipStream_t stream)
{
    const float* x    = (const float*)d_in[0];
    const float* adjs = (const float*)d_in[1];
    const float* W    = (const float*)d_in[2];
    float* out = (float*)d_out;
    unsigned short* xwt = (unsigned short*)d_ws;   // needs 3*256*8192*2 = 12.6 MB

    hipMemsetAsync(d_out, 0, (size_t)out_size * sizeof(float), stream);

    dim3 gA(NN / 16, RR);
    xw_kernel<<<gA, 256, 0, stream>>>(x, W, xwt);

    dim3 gB(NN / BM, RR * SPLIT);
    rgcn_spmm<<<gB, 512, 0, stream>>>(adjs, xwt, out);
}